// Round 3
// baseline (135.636 us; speedup 1.0000x reference)
//
#include <hip/hip_runtime.h>
#include <hip/hip_bf16.h>

// Problem constants
#define B_   16
#define N_   128
#define H_   32
#define D_   5
#define NEF_ 3
#define NE1  1537   // NUM_EDGES + 1
#define NP1  129    // N + 1

// ---------------------------------------------------------------------------
// Kernel 1: fused[d][idx][k] = sum_h edge_encoder_w[idx][h] * Wdis[d][h][k]
// Output in bf16 (halves main-kernel gather bytes; error ~2e-5 vs 0.1775 thr).
// ---------------------------------------------------------------------------
__global__ __launch_bounds__(256) void fused_tab_kernel(
    const float* __restrict__ edge_encoder_w,   // (1537, 32)
    const float* __restrict__ edge_dis_w,       // (131072,)
    __hip_bfloat16* __restrict__ fused)         // (5, 1537, 32) bf16
{
    __shared__ float wd[32 * 32];
    const int tid = threadIdx.x;
    const int bx  = blockIdx.x;
    const int d     = bx / 193;
    const int chunk = bx % 193;

    const float* wsrc = edge_dis_w + d * 1024;
    for (int k = tid; k < 1024; k += 256) wd[k] = wsrc[k];
    __syncthreads();

    const int g    = tid >> 5;
    const int lane = tid & 31;       // lane = output index k
    const int idx  = chunk * 8 + g;
    if (idx >= NE1) return;

    float w = edge_encoder_w[idx * 32 + lane];
    float acc = 0.f;
    #pragma unroll
    for (int hh = 0; hh < 32; ++hh) {
        acc += __shfl(w, hh, 32) * wd[hh * 32 + lane];
    }
    fused[(d * NE1 + idx) * 32 + lane] = __float2bfloat16(acc);
}

// ---------------------------------------------------------------------------
// Kernel 2: inner cells (i,j in [1,128]).
// ONE WAVE PER CELL: the 15 edge indices become wave-uniform scalars via
// v_readlane (no ds_bpermute), row addresses computed on the scalar unit,
// gathers issued as saddr-form global loads (SGPR base + 4*h voffset).
// Phase 1 runs on lanes 0..31 (h = lane); results staged in padded LDS tile
// for coalesced j-major stores in phase 2.
// Block = 256 thr = 4 waves; each wave loops 8 consecutive j cells.
// Grid: B * 128 * 4 = 8192 blocks.
// ---------------------------------------------------------------------------
__global__ __launch_bounds__(256) void main_kernel(
    const float* __restrict__ attn_bias,       // (16, 129, 129)
    const int*   __restrict__ spatial_pos,     // (16, 128, 128)
    const int*   __restrict__ edge_input,      // (16, 128, 128, 5, 3)
    const float* __restrict__ structural_w,    // (512, 32)
    const __hip_bfloat16* __restrict__ fused,  // (5, 1537, 32) bf16
    float* __restrict__ out)                   // (16, 32, 129, 129)
{
    __shared__ float tile[32][33];             // [h][j_local], +1 pad

    const int bx   = blockIdx.x;
    const int jt   = bx & 3;                   // j tile (32 j's)
    const int i    = (bx >> 2) & 127;
    const int b    = bx >> 9;
    const int tid  = threadIdx.x;
    const int wave = tid >> 6;                 // 0..3
    const int lane = tid & 63;
    const int h    = lane & 31;

    #pragma unroll
    for (int jj = 0; jj < 8; ++jj) {
        const int jl = wave * 8 + jj;          // 0..31
        const int j  = jt * 32 + jl;
        // wave-uniform cell index; readfirstlane pins it to an SGPR so the
        // per-cell loads below become s_load / saddr-form global loads
        int cell = (b * N_ + i) * N_ + j;
        cell = __builtin_amdgcn_readfirstlane(cell);

        const int sp0 = spatial_pos[cell];                 // uniform -> s_load
        const int* eip = edge_input + cell * (D_ * NEF_);  // uniform base
        int idx_v = 0;
        if (lane < 15) idx_v = eip[lane];                  // 15 ints, one vec load

        if (lane < 32) {
            float acc = 0.f;
            #pragma unroll
            for (int t = 0; t < 15; ++t) {
                const int id = __builtin_amdgcn_readlane(idx_v, t);  // SGPR
                const int d  = t / 3;                                // const
                const __hip_bfloat16* row = fused + (d * NE1 + id) * 32;
                acc += __bfloat162float(row[h]);
            }
            int s = sp0;
            if (s == 0) s = 1;
            if (s > 1)  s -= 1;
            if (s > D_) s = D_;
            const float val = acc / (3.0f * (float)s)
                            + structural_w[sp0 * 32 + h];
            tile[h][jl] = val;
        }
    }
    __syncthreads();

    // Phase 2: coalesced stores. 8 groups of 32 lanes; lane = j offset.
    const int g2    = tid >> 5;
    const int lane2 = tid & 31;
    const int j = jt * 32 + lane2 + 1;                     // output j in [1,128]
    const float ab2 = 2.0f * attn_bias[(b * NP1 + (i + 1)) * NP1 + j];
    #pragma unroll
    for (int rr = 0; rr < 4; ++rr) {
        const int hh = g2 + rr * 8;
        out[((b * H_ + hh) * NP1 + (i + 1)) * NP1 + j] = ab2 + tile[hh][lane2];
    }
}

// ---------------------------------------------------------------------------
// Kernel 3: borders. Row i=0 (all j) and column j=0 (i>=1):
//   out = 2*attn_bias + virt_w[h]
// ---------------------------------------------------------------------------
__global__ __launch_bounds__(256) void border_kernel(
    const float* __restrict__ attn_bias,    // (16, 129, 129)
    const float* __restrict__ virt_w,       // (1, 32)
    float* __restrict__ out)                // (16, 32, 129, 129)
{
    const int bh = blockIdx.x;              // 0..511
    const int b = bh >> 5;
    const int h = bh & 31;
    const float t = virt_w[h];

    float*       ob = out + (b * H_ + h) * NP1 * NP1;
    const float* ab = attn_bias + b * NP1 * NP1;

    for (int idx = threadIdx.x; idx < NP1 + N_; idx += 256) {
        if (idx < NP1) {
            ob[idx] = 2.0f * ab[idx] + t;
        } else {
            const int i = idx - 128;
            ob[i * NP1] = 2.0f * ab[i * NP1] + t;
        }
    }
}

// ---------------------------------------------------------------------------
extern "C" void kernel_launch(void* const* d_in, const int* in_sizes, int n_in,
                              void* d_out, int out_size, void* d_ws, size_t ws_size,
                              hipStream_t stream) {
    // 0: x (unused)  1: attn_bias  2: spatial_pos  3: edge_input
    // 4: edge_encoder_w  5: structural_w  6: edge_dis_w  7: virt_w
    const float* attn_bias      = (const float*)d_in[1];
    const int*   spatial_pos    = (const int*)  d_in[2];
    const int*   edge_input     = (const int*)  d_in[3];
    const float* edge_encoder_w = (const float*)d_in[4];
    const float* structural_w   = (const float*)d_in[5];
    const float* edge_dis_w     = (const float*)d_in[6];
    const float* virt_w         = (const float*)d_in[7];
    float* out = (float*)d_out;
    __hip_bfloat16* fused = (__hip_bfloat16*)d_ws;  // 5*1537*32*2 = 491,840 B

    hipLaunchKernelGGL(fused_tab_kernel, dim3(5 * 193), dim3(256), 0, stream,
                       edge_encoder_w, edge_dis_w, fused);
    hipLaunchKernelGGL(main_kernel, dim3(B_ * N_ * 4), dim3(256), 0, stream,
                       attn_bias, spatial_pos, edge_input, structural_w, fused, out);
    hipLaunchKernelGGL(border_kernel, dim3(B_ * H_), dim3(256), 0, stream,
                       attn_bias, virt_w, out);
}

// Round 4
// 117.968 us; speedup vs baseline: 1.1498x; 1.1498x over previous
//
#include <hip/hip_runtime.h>
#include <hip/hip_bf16.h>

// Problem constants
#define B_   16
#define N_   128
#define H_   32
#define D_   5
#define NEF_ 3
#define NE1  1537   // NUM_EDGES + 1
#define NP1  129    // N + 1

// ---------------------------------------------------------------------------
// Kernel 1: fused[d][idx][k] = sum_h edge_encoder_w[idx][h] * Wdis[d][h][k]
// bf16 output: halves main-kernel gather bytes; error ~2e-5 vs 0.1775 thr.
// ---------------------------------------------------------------------------
__global__ __launch_bounds__(256) void fused_tab_kernel(
    const float* __restrict__ edge_encoder_w,   // (1537, 32)
    const float* __restrict__ edge_dis_w,       // (131072,)
    __hip_bfloat16* __restrict__ fused)         // (5, 1537, 32) bf16
{
    __shared__ float wd[32 * 32];
    const int tid = threadIdx.x;
    const int bx  = blockIdx.x;
    const int d     = bx / 193;
    const int chunk = bx % 193;

    const float* wsrc = edge_dis_w + d * 1024;
    for (int k = tid; k < 1024; k += 256) wd[k] = wsrc[k];
    __syncthreads();

    const int g    = tid >> 5;
    const int lane = tid & 31;       // lane = output index k
    const int idx  = chunk * 8 + g;
    if (idx >= NE1) return;

    float w = edge_encoder_w[idx * 32 + lane];
    float acc = 0.f;
    #pragma unroll
    for (int hh = 0; hh < 32; ++hh) {
        acc += __shfl(w, hh, 32) * wd[hh * 32 + lane];
    }
    fused[(d * NE1 + idx) * 32 + lane] = __float2bfloat16(acc);
}

// ---------------------------------------------------------------------------
// Kernel 2: inner cells (i,j in [1,128]).
// One 64-lane wave handles a PAIR of adjacent cells: lanes 0..31 = cell A
// (h = lane), lanes 32..63 = cell B (h = lane-32). The pair's 30 edge
// indices sit at a wave-uniform address -> s_load; row-offset math -> SALU.
// Per-lane row select via mask trick: off = (delta & mhi) + offA + 2h
// (v_and + v_add3, no bpermute/cndmask). Gathers: global_load_ushort from
// the bf16 fused table (one 64B row per half-wave).
// Block = 256 thr = 4 waves; each wave does 4 pairs (8 cells). Grid: 8192.
// ---------------------------------------------------------------------------
__global__ __launch_bounds__(256) void main_kernel(
    const float* __restrict__ attn_bias,       // (16, 129, 129)
    const int*   __restrict__ spatial_pos,     // (16, 128, 128)
    const int*   __restrict__ edge_input,      // (16, 128, 128, 5, 3)
    const float* __restrict__ structural_w,    // (512, 32)
    const __hip_bfloat16* __restrict__ fused,  // (5, 1537, 32) bf16
    float* __restrict__ out)                   // (16, 32, 129, 129)
{
    __shared__ float tile[32][33];             // [h][j_local], +1 pad

    const int bx   = blockIdx.x;
    const int jt   = bx & 3;                   // j tile (32 j's)
    const int i    = (bx >> 2) & 127;
    const int b    = bx >> 9;
    const int tid  = threadIdx.x;
    const int wv   = __builtin_amdgcn_readfirstlane(tid >> 6);  // 0..3, SGPR
    const int lane = tid & 63;
    const int h    = lane & 31;
    const int hi   = (lane >> 5) & 1;          // 0 = cell A, 1 = cell B
    const int mhi  = -hi;                      // 0 or 0xFFFFFFFF
    const int h2   = h * 2;                    // byte offset in bf16 row
    const int h4   = h * 4;                    // byte offset in fp32 row

    // wave-uniform first cell of this wave's 8-cell span
    const int cell0 = (b * N_ + i) * N_ + jt * 32 + wv * 8;

    #pragma unroll
    for (int pj = 0; pj < 4; ++pj) {
        const int cellA = cell0 + 2 * pj;                  // uniform
        const int* eip  = edge_input + cellA * (D_ * NEF_);// uniform -> s_load
        const int spA = spatial_pos[cellA];                // uniform -> s_load
        const int spB = spatial_pos[cellA + 1];

        float acc = 0.f;
        #pragma unroll
        for (int t = 0; t < 15; ++t) {
            const int dbase = (t / 3) * NE1;               // compile-time
            const int offA  = (dbase + eip[t])      << 6;  // SALU (uniform)
            const int offB  = (dbase + eip[15 + t]) << 6;  // SALU (uniform)
            const int delta = offB - offA;                 // SALU
            const int off   = (delta & mhi) + offA + h2;   // v_and + v_add3
            const unsigned short u =
                *(const unsigned short*)((const char*)fused + off);
            union { unsigned int ui; float f; } cv;
            cv.ui = ((unsigned int)u) << 16;               // bf16 -> f32
            acc += cv.f;
        }

        // spatial transform (uniform per cell, scalar-friendly)
        int sA = (spA == 0) ? 1 : spA; if (sA > 1) sA -= 1; if (sA > D_) sA = D_;
        int sB = (spB == 0) ? 1 : spB; if (sB > 1) sB -= 1; if (sB > D_) sB = D_;
        const float invA = __builtin_amdgcn_rcpf(3.0f * (float)sA);
        const float invB = __builtin_amdgcn_rcpf(3.0f * (float)sB);
        const float inv  = hi ? invB : invA;

        // structural_w row gather (once per pair)
        const int spoff = ((((spB - spA) & mhi) + spA) << 7) + h4;
        const float st = *(const float*)((const char*)structural_w + spoff);

        tile[h][wv * 8 + 2 * pj + hi] = acc * inv + st;
    }
    __syncthreads();

    // Phase 2: coalesced stores. 8 groups of 32 lanes; lane = j offset.
    const int g2 = tid >> 5;
    const int l2 = tid & 31;
    const int j  = jt * 32 + l2 + 1;                       // output j in [1,128]
    const float ab2 = 2.0f * attn_bias[(b * NP1 + (i + 1)) * NP1 + j];
    #pragma unroll
    for (int rr = 0; rr < 4; ++rr) {
        const int hh = g2 + rr * 8;
        out[((b * H_ + hh) * NP1 + (i + 1)) * NP1 + j] = ab2 + tile[hh][l2];
    }
}

// ---------------------------------------------------------------------------
// Kernel 3: borders. Row i=0 (all j) and column j=0 (i>=1):
//   out = 2*attn_bias + virt_w[h]
// ---------------------------------------------------------------------------
__global__ __launch_bounds__(256) void border_kernel(
    const float* __restrict__ attn_bias,    // (16, 129, 129)
    const float* __restrict__ virt_w,       // (1, 32)
    float* __restrict__ out)                // (16, 32, 129, 129)
{
    const int bh = blockIdx.x;              // 0..511
    const int b = bh >> 5;
    const int h = bh & 31;
    const float t = virt_w[h];

    float*       ob = out + (b * H_ + h) * NP1 * NP1;
    const float* ab = attn_bias + b * NP1 * NP1;

    for (int idx = threadIdx.x; idx < NP1 + N_; idx += 256) {
        if (idx < NP1) {
            ob[idx] = 2.0f * ab[idx] + t;
        } else {
            const int i = idx - 128;
            ob[i * NP1] = 2.0f * ab[i * NP1] + t;
        }
    }
}

// ---------------------------------------------------------------------------
extern "C" void kernel_launch(void* const* d_in, const int* in_sizes, int n_in,
                              void* d_out, int out_size, void* d_ws, size_t ws_size,
                              hipStream_t stream) {
    // 0: x (unused)  1: attn_bias  2: spatial_pos  3: edge_input
    // 4: edge_encoder_w  5: structural_w  6: edge_dis_w  7: virt_w
    const float* attn_bias      = (const float*)d_in[1];
    const int*   spatial_pos    = (const int*)  d_in[2];
    const int*   edge_input     = (const int*)  d_in[3];
    const float* edge_encoder_w = (const float*)d_in[4];
    const float* structural_w   = (const float*)d_in[5];
    const float* edge_dis_w     = (const float*)d_in[6];
    const float* virt_w         = (const float*)d_in[7];
    float* out = (float*)d_out;
    __hip_bfloat16* fused = (__hip_bfloat16*)d_ws;  // 5*1537*32*2 = 491,840 B

    hipLaunchKernelGGL(fused_tab_kernel, dim3(5 * 193), dim3(256), 0, stream,
                       edge_encoder_w, edge_dis_w, fused);
    hipLaunchKernelGGL(main_kernel, dim3(B_ * N_ * 4), dim3(256), 0, stream,
                       attn_bias, spatial_pos, edge_input, structural_w, fused, out);
    hipLaunchKernelGGL(border_kernel, dim3(B_ * H_), dim3(256), 0, stream,
                       attn_bias, virt_w, out);
}